// Round 3
// baseline (438.286 us; speedup 1.0000x reference)
//
#include <hip/hip_runtime.h>
#include <math.h>

#define NB 512
#define LL 33
#define DD 4096
#define PP 64
#define KK 512
#define HH 128
#define LN_EPS 1e-5f
#define NT 256

// monotone float->uint key: larger float => larger key
__device__ __forceinline__ unsigned fkey(float s) {
    unsigned u = __float_as_uint(s);
    return (u & 0x80000000u) ? ~u : (u | 0x80000000u);
}

__device__ __forceinline__ float waveMax(float v) {
    #pragma unroll
    for (int o = 32; o > 0; o >>= 1) v = fmaxf(v, __shfl_xor(v, o));
    return v;
}
__device__ __forceinline__ float waveSum(float v) {
    #pragma unroll
    for (int o = 32; o > 0; o >>= 1) v += __shfl_xor(v, o);
    return v;
}

__global__ __launch_bounds__(NT) void sda_kernel(
    const float* __restrict__ x,
    const float* __restrict__ Wp, const float* __restrict__ bp,
    const float* __restrict__ ws, const float* __restrict__ bsp,
    const float* __restrict__ gamma, const float* __restrict__ beta,
    const float* __restrict__ W1, const float* __restrict__ b1,
    const float* __restrict__ W2, const float* __restrict__ b2,
    float* __restrict__ out)
{
    __shared__ __align__(16) float s_w[DD];        // scores -> unnormalized weights
    __shared__ __align__(16) float s_xc[LL * 256]; // column-cache: x[b, l, 0:256]
    __shared__ float s_v[LL];
    __shared__ unsigned s_hist[4][256];
    __shared__ unsigned s_scanA[256];
    __shared__ unsigned s_scanB[256];
    __shared__ float s_red[4];
    __shared__ float s_y[LL];
    __shared__ float s_o[PP];
    __shared__ float s_g[HH];
    __shared__ float s_c, s_m, s_S;
    __shared__ unsigned s_prefix, s_kk, s_ceq;

    const int t = threadIdx.x;
    const int lane = t & 63;
    const int wv = t >> 6;
    const int b = blockIdx.x;
    const float* __restrict__ xb = x + (size_t)b * (LL * DD);

    // fold scoring: v[l] = sum_p Wp[p,l]*ws[p];  c = sum_p ws[p]*bp[p] + bs
    if (t < LL) {
        float a = 0.f;
        for (int p = 0; p < PP; ++p) a += Wp[p * LL + t] * ws[p];
        s_v[t] = a;
    } else if (t == LL) {
        float a = bsp[0];
        for (int p = 0; p < PP; ++p) a += ws[p] * bp[p];
        s_c = a;
    }
    if (t == 0) { s_prefix = 0u; s_kk = KK; s_ceq = 0u; }
    __syncthreads();

    // ---- phase A: scores[d] = v . x[b,:,d] + c  (float4-vectorized, coalesced)
    const float c0 = s_c;
    float4* s_w4 = (float4*)s_w;
    float4* s_xc4 = (float4*)s_xc;   // [l*64 + f], f in float4 units, cols 0..255
    float4 acc[4];
    #pragma unroll
    for (int i = 0; i < 4; ++i) acc[i] = make_float4(c0, c0, c0, c0);
    for (int l = 0; l < LL; ++l) {
        const float vl = s_v[l];
        const float4* row = (const float4*)(xb + l * DD);
        const float4 xv0 = row[t];
        const float4 xv1 = row[t + NT];
        const float4 xv2 = row[t + 2 * NT];
        const float4 xv3 = row[t + 3 * NT];
        if (t < 64) s_xc4[l * 64 + t] = xv0;   // cache cols 0..255 of row l
        acc[0].x += vl * xv0.x; acc[0].y += vl * xv0.y; acc[0].z += vl * xv0.z; acc[0].w += vl * xv0.w;
        acc[1].x += vl * xv1.x; acc[1].y += vl * xv1.y; acc[1].z += vl * xv1.z; acc[1].w += vl * xv1.w;
        acc[2].x += vl * xv2.x; acc[2].y += vl * xv2.y; acc[2].z += vl * xv2.z; acc[2].w += vl * xv2.w;
        acc[3].x += vl * xv3.x; acc[3].y += vl * xv3.y; acc[3].z += vl * xv3.z; acc[3].w += vl * xv3.w;
    }
    // keys stay in registers for all 4 radix rounds + the weight phase
    unsigned ukey[16];
    float lmax = -INFINITY;
    #pragma unroll
    for (int i = 0; i < 4; ++i) {
        s_w4[t + i * NT] = acc[i];   // scores to LDS (serial tie-fallback needs them)
        ukey[4 * i + 0] = fkey(acc[i].x);
        ukey[4 * i + 1] = fkey(acc[i].y);
        ukey[4 * i + 2] = fkey(acc[i].z);
        ukey[4 * i + 3] = fkey(acc[i].w);
        lmax = fmaxf(fmaxf(lmax, fmaxf(acc[i].x, acc[i].y)), fmaxf(acc[i].z, acc[i].w));
    }
    lmax = waveMax(lmax);
    if (lane == 0) s_red[wv] = lmax;
    __syncthreads();
    if (t == 0) s_m = fmaxf(fmaxf(s_red[0], s_red[1]), fmaxf(s_red[2], s_red[3]));
    __syncthreads();

    // ---- exact radix-select of the K-th largest key (MSB->LSB, 8 bits/round)
    for (int shift = 24; shift >= 0; shift -= 8) {
        for (int i = t; i < 4 * 256; i += NT) ((unsigned*)s_hist)[i] = 0u;
        __syncthreads();
        const unsigned pfx = s_prefix;
        const unsigned hm = (shift == 24) ? 0u : (0xFFFFFFFFu << (shift + 8));
        #pragma unroll
        for (int i = 0; i < 16; ++i) {
            const unsigned u = ukey[i];
            if ((u & hm) == pfx)
                atomicAdd(&s_hist[wv][(u >> shift) & 255u], 1u);
        }
        __syncthreads();
        s_scanA[t] = s_hist[0][t] + s_hist[1][t] + s_hist[2][t] + s_hist[3][t];
        __syncthreads();
        // suffix (descending cumulative) sum, double-buffered: 1 barrier/step
        unsigned* src = s_scanA;
        unsigned* dst = s_scanB;
        for (int off = 1; off < 256; off <<= 1) {
            dst[t] = src[t] + ((t + off < 256) ? src[t + off] : 0u);
            __syncthreads();
            unsigned* tmp = src; src = dst; dst = tmp;
        }
        const unsigned kk = s_kk;
        const unsigned mine = src[t];
        const unsigned above = (t == 255) ? 0u : src[t + 1];
        __syncthreads();
        if (mine >= kk && above < kk) {   // exactly one thread/bin crosses
            s_prefix = pfx | ((unsigned)t << shift);
            s_kk = kk - above;            // remaining rank within equal keys
            s_ceq = mine - above;         // count of keys == chosen prefix
        }
        __syncthreads();
    }
    const unsigned T = s_prefix;
    const unsigned need_eq = s_kk;     // how many key==T elements belong to top-K
    const unsigned count_eq = s_ceq;   // how many key==T elements exist
    const float m = s_m;

    // ---- unnormalized softmax weights in place (dense over d)
    if (count_eq == need_eq) {         // common path: take all ties
        float lsum = 0.f;
        #pragma unroll
        for (int i = 0; i < 4; ++i) {
            float4 w;
            w.x = (ukey[4 * i + 0] >= T) ? expf(acc[i].x - m) : 0.f;
            w.y = (ukey[4 * i + 1] >= T) ? expf(acc[i].y - m) : 0.f;
            w.z = (ukey[4 * i + 2] >= T) ? expf(acc[i].z - m) : 0.f;
            w.w = (ukey[4 * i + 3] >= T) ? expf(acc[i].w - m) : 0.f;
            s_w4[t + i * NT] = w;
            lsum += w.x + w.y + w.z + w.w;
        }
        lsum = waveSum(lsum);
        if (lane == 0) s_red[wv] = lsum;
        __syncthreads();
        if (t == 0) s_S = s_red[0] + s_red[1] + s_red[2] + s_red[3];
        __syncthreads();
    } else {
        // rare tie-at-threshold path: serial, exact lowest-index tie-break
        __syncthreads();
        if (t == 0) {
            unsigned taken = 0;
            float S = 0.f;
            for (int d = 0; d < DD; ++d) {
                const float s = s_w[d];
                const unsigned u = fkey(s);
                float w = 0.f;
                if (u > T) w = expf(s - m);
                else if (u == T && taken < need_eq) { w = expf(s - m); ++taken; }
                s_w[d] = w;
                S += w;
            }
            s_S = S;
        }
        __syncthreads();
    }
    const float invS = 1.0f / s_S;

    // ---- y[l] = sum_d w[d] * x[b,l,d]  (one l per wave, coalesced re-read;
    //      cols 0..255 come from the LDS cache instead of HBM)
    for (int l = wv; l < LL; l += 4) {
        const float4* row = (const float4*)(xb + l * DD);
        float a = 0.f;
        {
            const float4 xv = s_xc4[l * 64 + lane];
            const float4 w4 = s_w4[lane];
            a += w4.x * xv.x + w4.y * xv.y + w4.z * xv.z + w4.w * xv.w;
        }
        #pragma unroll
        for (int j = 1; j < 16; ++j) {
            const int f = lane + j * 64;
            const float4 xv = row[f];
            const float4 w4 = s_w4[f];
            a += w4.x * xv.x + w4.y * xv.y + w4.z * xv.z + w4.w * xv.w;
        }
        a = waveSum(a);
        if (lane == 0) s_y[l] = a;
    }
    __syncthreads();

    // ---- head: out = Wp*y*invS + bp ; LN ; GELU(W1+b1) ; W2+b2
    if (t < PP) {
        float a = 0.f;
        for (int l = 0; l < LL; ++l) a += Wp[t * LL + l] * s_y[l];
        s_o[t] = a * invS + bp[t];
    }
    __syncthreads();
    if (wv == 0) {
        const float o = s_o[lane];
        const float mu = waveSum(o) * (1.f / PP);
        const float dv = o - mu;
        const float var = waveSum(dv * dv) * (1.f / PP);
        s_o[lane] = dv * rsqrtf(var + LN_EPS) * gamma[lane] + beta[lane];
    }
    __syncthreads();
    if (t < HH) {
        float a = b1[t];
        for (int p = 0; p < PP; ++p) a += W1[t * PP + p] * s_o[p];
        s_g[t] = 0.5f * a * (1.f + erff(a * 0.70710678118654752440f));
    }
    __syncthreads();
    if (t < 2) {
        float a = b2[t];
        for (int j = 0; j < HH; ++j) a += W2[t * HH + j] * s_g[j];
        out[b * 2 + t] = a;
    }
}

extern "C" void kernel_launch(void* const* d_in, const int* in_sizes, int n_in,
                              void* d_out, int out_size, void* d_ws, size_t ws_size,
                              hipStream_t stream) {
    const float* x     = (const float*)d_in[0];
    const float* Wp    = (const float*)d_in[1];
    const float* bp    = (const float*)d_in[2];
    const float* ws    = (const float*)d_in[3];
    const float* bs    = (const float*)d_in[4];
    const float* gamma = (const float*)d_in[5];
    const float* beta  = (const float*)d_in[6];
    const float* W1    = (const float*)d_in[7];
    const float* b1    = (const float*)d_in[8];
    const float* W2    = (const float*)d_in[9];
    const float* b2    = (const float*)d_in[10];
    float* out = (float*)d_out;
    hipLaunchKernelGGL(sda_kernel, dim3(NB), dim3(NT), 0, stream,
                       x, Wp, bp, ws, bs, gamma, beta, W1, b1, W2, b2, out);
}